// Round 3
// baseline (117.327 us; speedup 1.0000x reference)
//
#include <hip/hip_runtime.h>
#include <math.h>

// Problem constants
constexpr int kB = 2;
constexpr int kC = 128;
constexpr int kN = 784;
constexpr float kInvT = 1.0f / 11.313708498984761f;  // 1/sqrt(C)
constexpr float kInvC = 1.0f / 128.0f;

constexpr size_t kOutElems  = (size_t)kB * kC * kN;  // 200704
constexpr size_t kAttnElems = (size_t)kB * kN * kN;  // 1229312

typedef _Float16 h2 __attribute__((ext_vector_type(2)));
typedef _Float16 half8v __attribute__((ext_vector_type(8)));
typedef float f32x4 __attribute__((ext_vector_type(4)));

__device__ inline h2 u2h(unsigned u) { union { unsigned u; h2 h; } x; x.u = u; return x.h; }
__device__ inline unsigned h2u(h2 h) { union { unsigned u; h2 h; } x; x.h = h; return x.u; }

__device__ inline float wave_max(float v) {
#pragma unroll
    for (int o = 32; o > 0; o >>= 1) v = fmaxf(v, __shfl_xor(v, o, 64));
    return v;
}
__device__ inline float wave_sum(float v) {
#pragma unroll
    for (int o = 32; o > 0; o >>= 1) v += __shfl_xor(v, o, 64);
    return v;
}

// ================= Kernel 1: D[b,k,q] = sum_c |q[c,q]/T - k[c,k]| (raw fp32 sums) =========
// Packed-fp16 math: per c and per 2 q-elems: v_pk_add(neg) + v_and(absmask) + v_pk_add
// = 3 insts/2 elems (1.33x the fp32 VALU core). fp16 accs segmented every 32 c into fp32
// masters (dD ~ 0.1 on ~100 row-sums -> attn err ~1e-6, negligible).
// Full 128-c per block (no half-split): D1 array + softmax W-pass eliminated.
// Tile 32k x 64q, grid 2b*25kt*13qt = 650 blocks, LDS 32 KB (5 resident, 2.54/CU avg).
// k staged as duplicated fp16 pairs (k,k); q staged as (q0,q1) pairs, pre-scaled 1/T.
// All LDS patterns bank-uniform at stride 32 (reads broadcast per 32-lane group).
constexpr int TKD = 32;
constexpr int TQD = 64;
constexpr int NKTD = (kN + TKD - 1) / TKD;  // 25 (last tile rows 784.. guarded)
constexpr int NQTD = (kN + TQD - 1) / TQD;  // 13
constexpr int KSTR = 32;                    // uint32 row stride (uniform banks, no pad)

__global__ __launch_bounds__(256) void dist_kernel(const float* __restrict__ qg,
                                                   const float* __restrict__ kg,
                                                   float* __restrict__ D) {
    int bid = blockIdx.x;
    const int qt = bid % NQTD; bid /= NQTD;
    const int kt = bid % NKTD; bid /= NKTD;
    const int b  = bid;
    const int k0 = kt * TKD;
    const int q0 = qt * TQD;
    const int t  = threadIdx.x;

    __shared__ unsigned ks2[kC][KSTR];  // 16 KB: dup pairs (k,k)
    __shared__ unsigned qs2[kC][KSTR];  // 16 KB: pairs (q0,q1)

    const float* kb = kg + (size_t)b * kC * kN;
    const float* qb = qg + (size_t)b * kC * kN;

    // Stage k: 128c x 8 float4 groups (4 iters). Store b128 of 4 dup-pairs.
#pragma unroll
    for (int i = t; i < kC * 8; i += 256) {
        const int c = i >> 3, g = i & 7;
        const float4 kv =
            *reinterpret_cast<const float4*>(kb + (size_t)c * kN + min(k0 + 4 * g, kN - 4));
        uint4 d;
        h2 p;
        p[0] = p[1] = (_Float16)kv.x; d.x = h2u(p);
        p[0] = p[1] = (_Float16)kv.y; d.y = h2u(p);
        p[0] = p[1] = (_Float16)kv.z; d.z = h2u(p);
        p[0] = p[1] = (_Float16)kv.w; d.w = h2u(p);
        *reinterpret_cast<uint4*>(&ks2[c][4 * g]) = d;
    }
    // Stage q: 128c x 16 float4 groups (8 iters). Scale 1/T, store b64 of 2 pairs.
#pragma unroll
    for (int i = t; i < kC * 16; i += 256) {
        const int c = i >> 4, g = i & 15;
        float4 qv =
            *reinterpret_cast<const float4*>(qb + (size_t)c * kN + min(q0 + 4 * g, kN - 4));
        qv.x *= kInvT; qv.y *= kInvT; qv.z *= kInvT; qv.w *= kInvT;
        uint2 d;
        h2 p;
        p[0] = (_Float16)qv.x; p[1] = (_Float16)qv.y; d.x = h2u(p);
        p[0] = (_Float16)qv.z; p[1] = (_Float16)qv.w; d.y = h2u(p);
        *reinterpret_cast<uint2*>(&qs2[c][2 * g]) = d;
    }
    __syncthreads();

    const int qgp = t & 31;  // q-pair index (b32 reads, perfectly bank-spread)
    const int kx  = t >> 5;  // k-quad index (b128 reads, 32-lane broadcast)

    float accM[4][2];
#pragma unroll
    for (int j = 0; j < 4; ++j) accM[j][0] = accM[j][1] = 0.0f;

#pragma unroll
    for (int seg = 0; seg < 4; ++seg) {
        h2 a0 = u2h(0), a1 = u2h(0), a2 = u2h(0), a3 = u2h(0);
#pragma unroll
        for (int cc = 0; cc < 32; ++cc) {
            const int c = seg * 32 + cc;
            const uint4 kd = *reinterpret_cast<const uint4*>(&ks2[c][4 * kx]);
            const h2 qp = u2h(qs2[c][qgp]);
            a0 += u2h(h2u(qp - u2h(kd.x)) & 0x7FFF7FFFu);
            a1 += u2h(h2u(qp - u2h(kd.y)) & 0x7FFF7FFFu);
            a2 += u2h(h2u(qp - u2h(kd.z)) & 0x7FFF7FFFu);
            a3 += u2h(h2u(qp - u2h(kd.w)) & 0x7FFF7FFFu);
        }
        accM[0][0] += (float)a0[0]; accM[0][1] += (float)a0[1];
        accM[1][0] += (float)a1[0]; accM[1][1] += (float)a1[1];
        accM[2][0] += (float)a2[0]; accM[2][1] += (float)a2[1];
        accM[3][0] += (float)a3[0]; accM[3][1] += (float)a3[1];
    }

    const int qcol = q0 + 2 * qgp;
    if (qcol < kN) {  // kN even: pair never straddles
#pragma unroll
        for (int j = 0; j < 4; ++j) {
            const int krow = k0 + 4 * kx + j;
            if (krow < kN) {
                *reinterpret_cast<float2*>(&D[((size_t)b * kN + krow) * kN + qcol]) =
                    make_float2(accM[j][0], accM[j][1]);
            }
        }
    }
}

// ================= Kernel 2: row softmax over q (raw sums -> attn) =================
__global__ __launch_bounds__(256) void softmax_kernel(float* __restrict__ A) {
    const size_t row = (size_t)blockIdx.x * kN;
    float4* A4 = reinterpret_cast<float4*>(A + row);
    const int t = threadIdx.x;
    const int lane = t & 63, wid = t >> 6;
    const bool act = t < (kN / 4);  // 196
    __shared__ float xred[4];

    float4 x = make_float4(-1e30f, -1e30f, -1e30f, -1e30f);
    if (act) x = A4[t];

    float m = fmaxf(fmaxf(x.x, x.y), fmaxf(x.z, x.w));
    m = wave_max(m);
    if (lane == 0) xred[wid] = m;
    __syncthreads();
    m = fmaxf(fmaxf(xred[0], xred[1]), fmaxf(xred[2], xred[3]));
    __syncthreads();

    float4 p;
    p.x = __expf((x.x - m) * kInvC);
    p.y = __expf((x.y - m) * kInvC);
    p.z = __expf((x.z - m) * kInvC);
    p.w = __expf((x.w - m) * kInvC);
    float lsum = p.x + p.y + p.z + p.w;  // inactive: exp(-huge)=0
    lsum = wave_sum(lsum);
    if (lane == 0) xred[wid] = lsum;
    __syncthreads();
    const float inv = 1.0f / (xred[0] + xred[1] + xred[2] + xred[3]);
    if (act) {
        p.x *= inv; p.y *= inv; p.z *= inv; p.w *= inv;
        A4[t] = p;
    }
}

// ================= Kernel 3: MFMA bmm, NO LDS / NO barriers, q-split partials ==========
// out[b,c,k] = sum_q v[b,c,q]*attn[b,k,q];  GEMM per batch: M=128(c), N=784(k), K=784(q).
// Fragments straight from global (attn/v L2-resident; 32B/lane contiguous per frag row),
// q split 7x128 -> grid 2b*2ct*13kt*7qs = 364 barrier-free blocks.
// Per wave: 16c x 64k tile, 4 ks-steps x {10 dwordx4 loads, cvt to fp16, 4 MFMA}.
// Fragment map (m89-verified): A row=lane&15, k=(lane>>4)*8+j; B col=lane&15, same k;
// D col=lane&15, row=(lane>>4)*4+reg.
constexpr int GN = 64;                    // k cols per block
constexpr int GK = 128;                   // q per slice
constexpr int QSP3 = (kN + GK - 1) / GK;  // 7 (last slice: 16 valid q)
constexpr int NKT3 = (kN + GN - 1) / GN;  // 13

__device__ inline half8v to_h8(const float4 a, const float4 b) {
    half8v h;
    h[0] = (_Float16)a.x; h[1] = (_Float16)a.y; h[2] = (_Float16)a.z; h[3] = (_Float16)a.w;
    h[4] = (_Float16)b.x; h[5] = (_Float16)b.y; h[6] = (_Float16)b.z; h[7] = (_Float16)b.w;
    return h;
}

template <bool ATOMIC>
__global__ __launch_bounds__(256) void bmm_mfma(const float* __restrict__ vg,
                                                const float* __restrict__ attn,
                                                float* __restrict__ P) {
    int bid = blockIdx.x;
    const int qs = bid % QSP3; bid /= QSP3;
    const int kt = bid % NKT3; bid /= NKT3;
    const int ct = bid & 1;    bid >>= 1;
    const int b  = bid;
    const int k0 = kt * GN;
    const int c0 = ct * 64;
    const int q0 = qs * GK;
    const int t  = threadIdx.x;
    const int lane = t & 63;
    const int w = t >> 6;

    const int lrow = lane & 15;           // frag row/col within 16
    const int kgrp = (lane >> 4) * 8;     // q offset of this lane's 8 k-elems

    // Per-lane base pointers (OOB attn rows clamped; junk cols discarded at store).
    const float* vp = vg + (((size_t)b * kC + c0 + 16 * w + lrow) * kN + q0 + kgrp);
    const float* ap[4];
#pragma unroll
    for (int n = 0; n < 4; ++n) {
        const int krow = min(k0 + 16 * n + lrow, kN - 1);
        ap[n] = attn + (((size_t)b * kN + krow) * kN + q0 + kgrp);
    }

    f32x4 acc[4] = {};  // 4 n-frags: wave owns 16 c-rows x 64 k-cols

    if (q0 + GK <= kN) {  // full slice: 4 ks-steps, no predication
#pragma unroll
        for (int ks = 0; ks < GK / 32; ++ks) {
            const int qb = ks * 32;
            const half8v av = to_h8(*reinterpret_cast<const float4*>(vp + qb),
                                    *reinterpret_cast<const float4*>(vp + qb + 4));
#pragma unroll
            for (int n = 0; n < 4; ++n) {
                const half8v bv = to_h8(*reinterpret_cast<const float4*>(ap[n] + qb),
                                        *reinterpret_cast<const float4*>(ap[n] + qb + 4));
                acc[n] = __builtin_amdgcn_mfma_f32_16x16x32_f16(av, bv, acc[n], 0, 0, 0);
            }
        }
    } else {  // tail slice (qs==6): only ks=0 has data; predicate lanes past kN
        const float4 z = make_float4(0.f, 0.f, 0.f, 0.f);
        const bool ok = (q0 + kgrp) < kN;  // spans of 8 never straddle kN (784%16==0)
        const half8v av = to_h8(ok ? *reinterpret_cast<const float4*>(vp) : z,
                                ok ? *reinterpret_cast<const float4*>(vp + 4) : z);
#pragma unroll
        for (int n = 0; n < 4; ++n) {
            const half8v bv = to_h8(ok ? *reinterpret_cast<const float4*>(ap[n]) : z,
                                    ok ? *reinterpret_cast<const float4*>(ap[n] + 4) : z);
            acc[n] = __builtin_amdgcn_mfma_f32_16x16x32_f16(av, bv, acc[n], 0, 0, 0);
        }
    }

    // Epilogue: D col=lane&15, row=(lane>>4)*4+r. Store partial slice (or atomicAdd).
    const int crow = c0 + 16 * w + (lane >> 4) * 4;
    const int kc = k0 + lrow;
#pragma unroll
    for (int n = 0; n < 4; ++n) {
        const int kcol = kc + 16 * n;
        if (kcol < kN) {
            if (ATOMIC) {
#pragma unroll
                for (int r = 0; r < 4; ++r)
                    atomicAdd(&P[((size_t)b * kC + crow + r) * kN + kcol], acc[n][r]);
            } else {
                float* op = P + (((size_t)qs * kB + b) * kC + crow) * kN + kcol;
#pragma unroll
                for (int r = 0; r < 4; ++r) op[(size_t)r * kN] = acc[n][r];
            }
        }
    }
}

// ================= Kernel 4: out = sum_qs partial[qs] =================
// 196 blocks x 256 threads; one float4 per thread; slices L2/L3-resident.
__global__ __launch_bounds__(256) void reduce_kernel(const float* __restrict__ P,
                                                     float* __restrict__ out) {
    const int idx = blockIdx.x * 256 + threadIdx.x;  // < 50176 exactly
    const float4* p = reinterpret_cast<const float4*>(P) + idx;
    float4 s = p[0];
#pragma unroll
    for (int qs = 1; qs < QSP3; ++qs) {
        const float4 v = p[(size_t)qs * (kOutElems / 4)];
        s.x += v.x; s.y += v.y; s.z += v.z; s.w += v.w;
    }
    reinterpret_cast<float4*>(out)[idx] = s;
}

extern "C" void kernel_launch(void* const* d_in, const int* in_sizes, int n_in,
                              void* d_out, int out_size, void* d_ws, size_t ws_size,
                              hipStream_t stream) {
    const float* q = (const float*)d_in[0];
    const float* k = (const float*)d_in[1];
    const float* v = (const float*)d_in[2];

    float* out  = (float*)d_out;               // [B, C, N]
    float* attn = out + kOutElems;             // [B, N, N]
    float* P    = (float*)d_ws;                // [QSP3][B, C, N] partials

    const size_t need = (size_t)QSP3 * kOutElems * sizeof(float);

    if (ws_size >= need) {
        dist_kernel<<<kB * NKTD * NQTD, 256, 0, stream>>>(q, k, attn);
        softmax_kernel<<<kB * kN, 256, 0, stream>>>(attn);
        bmm_mfma<false><<<kB * 2 * NKT3 * QSP3, 256, 0, stream>>>(v, attn, P);
        reduce_kernel<<<(int)(kOutElems / 4 / 256), 256, 0, stream>>>(P, out);
    } else {
        // Fallback without workspace: bmm accumulates into zeroed out via atomics.
        hipMemsetAsync(out, 0, kOutElems * sizeof(float), stream);
        dist_kernel<<<kB * NKTD * NQTD, 256, 0, stream>>>(q, k, attn);
        softmax_kernel<<<kB * kN, 256, 0, stream>>>(attn);
        bmm_mfma<true><<<kB * 2 * NKT3 * QSP3, 256, 0, stream>>>(v, attn, out);
    }
}

// Round 4
// 95.257 us; speedup vs baseline: 1.2317x; 1.2317x over previous
//
#include <hip/hip_runtime.h>
#include <math.h>

// Problem constants
constexpr int kB = 2;
constexpr int kC = 128;
constexpr int kN = 784;
constexpr float kInvT = 1.0f / 11.313708498984761f;  // 1/sqrt(C)
constexpr float kInvC = 1.0f / 128.0f;

constexpr size_t kOutElems  = (size_t)kB * kC * kN;  // 200704
constexpr size_t kAttnElems = (size_t)kB * kN * kN;  // 1229312

typedef _Float16 half8v __attribute__((ext_vector_type(8)));
typedef float f32x4 __attribute__((ext_vector_type(4)));

__device__ inline float wave_max(float v) {
#pragma unroll
    for (int o = 32; o > 0; o >>= 1) v = fmaxf(v, __shfl_xor(v, o, 64));
    return v;
}
__device__ inline float wave_sum(float v) {
#pragma unroll
    for (int o = 32; o > 0; o >>= 1) v += __shfl_xor(v, o, 64);
    return v;
}

// ================= Kernel 1: D[b,k,q] = sum_c |q[c,q]/T - k[c,k]| (raw fp32 sums) =========
// Round-3 post-mortem: packed-fp16 full-unroll blew VGPR to 256 -> 7% occupancy,
// latency-bound, 45 us. Revert to the PROVEN fp32 core (2 VALU/elem, unroll 4,
// 8 fp32 accs) but keep CSP=1: full 128 c per block -> no D1 array, softmax single-pass.
// Tile 32k x 64q (4k x 2q per thread), grid 2b*25kt*13qt = 650 blocks.
// LDS = ks[128][36] + qs[128][68] = 52 KB -> 3 blocks/CU (12 waves), VALU-bound.
// Per c-iter: k b128 (2-addr broadcast, free) + q b64 (2-way, free) + 16 VALU.
constexpr int TKD = 32;
constexpr int TQD = 64;
constexpr int NKTD = (kN + TKD - 1) / TKD;  // 25 (rows 784..799 guarded)
constexpr int NQTD = (kN + TQD - 1) / TQD;  // 13
constexpr int KSTR = 36;                    // 32+4 pad
constexpr int QSTR = 68;                    // 64+4 pad

__global__ __launch_bounds__(256) void dist_kernel(const float* __restrict__ qg,
                                                   const float* __restrict__ kg,
                                                   float* __restrict__ D) {
    int bid = blockIdx.x;
    const int qt = bid % NQTD; bid /= NQTD;
    const int kt = bid % NKTD; bid /= NKTD;
    const int b  = bid;
    const int k0 = kt * TKD;
    const int q0 = qt * TQD;
    const int t  = threadIdx.x;

    __shared__ float ks[kC][KSTR];  // 18.4 KB
    __shared__ float qs[kC][QSTR];  // 34.8 KB

    const float* kb = kg + (size_t)b * kC * kN;
    const float* qb = qg + (size_t)b * kC * kN;

    // Stage k: 128 rows x 8 float4 groups (4 iters/thread).
#pragma unroll
    for (int i = t; i < kC * 8; i += 256) {
        const int c = i >> 3, g = (i & 7) << 2;
        *reinterpret_cast<float4*>(&ks[c][g]) =
            *reinterpret_cast<const float4*>(kb + (size_t)c * kN + min(k0 + g, kN - 4));
    }
    // Stage q: 128 rows x 16 float4 groups (8 iters/thread), pre-scaled 1/T.
#pragma unroll
    for (int i = t; i < kC * 16; i += 256) {
        const int c = i >> 4, g = (i & 15) << 2;
        float4 qv =
            *reinterpret_cast<const float4*>(qb + (size_t)c * kN + min(q0 + g, kN - 4));
        qv.x *= kInvT; qv.y *= kInvT; qv.z *= kInvT; qv.w *= kInvT;
        *reinterpret_cast<float4*>(&qs[c][g]) = qv;
    }
    __syncthreads();

    const int qgp = t & 31;  // q-pair index (b64 reads, 2-way = free)
    const int kx  = (t >> 5) << 2;  // k-quad base (b128, 32-lane broadcast)

    float acc[4][2];
#pragma unroll
    for (int j = 0; j < 4; ++j) acc[j][0] = acc[j][1] = 0.0f;

#pragma unroll 4
    for (int c = 0; c < kC; ++c) {
        const float4 kv = *reinterpret_cast<const float4*>(&ks[c][kx]);
        const float2 qv = *reinterpret_cast<const float2*>(&qs[c][2 * qgp]);
        const float kf[4] = {kv.x, kv.y, kv.z, kv.w};
#pragma unroll
        for (int j = 0; j < 4; ++j) {
            acc[j][0] += fabsf(qv.x - kf[j]);  // v_sub + v_add(abs)
            acc[j][1] += fabsf(qv.y - kf[j]);
        }
    }

    const int qcol = q0 + 2 * qgp;
    if (qcol < kN) {  // kN even: pair never straddles; q0+62 < 784 check via qcol
#pragma unroll
        for (int j = 0; j < 4; ++j) {
            const int krow = k0 + kx + j;
            if (krow < kN) {
                *reinterpret_cast<float2*>(&D[((size_t)b * kN + krow) * kN + qcol]) =
                    make_float2(acc[j][0], acc[j][1]);
            }
        }
    }
}

// ================= Kernel 2: row softmax over q (raw sums -> attn, in place) ==========
__global__ __launch_bounds__(256) void softmax_kernel(float* __restrict__ A) {
    const size_t row = (size_t)blockIdx.x * kN;
    float4* A4 = reinterpret_cast<float4*>(A + row);
    const int t = threadIdx.x;
    const int lane = t & 63, wid = t >> 6;
    const bool act = t < (kN / 4);  // 196
    __shared__ float xred[4];

    float4 x = make_float4(-1e30f, -1e30f, -1e30f, -1e30f);
    if (act) x = A4[t];

    float m = fmaxf(fmaxf(x.x, x.y), fmaxf(x.z, x.w));
    m = wave_max(m);
    if (lane == 0) xred[wid] = m;
    __syncthreads();
    m = fmaxf(fmaxf(xred[0], xred[1]), fmaxf(xred[2], xred[3]));
    __syncthreads();

    float4 p;
    p.x = __expf((x.x - m) * kInvC);
    p.y = __expf((x.y - m) * kInvC);
    p.z = __expf((x.z - m) * kInvC);
    p.w = __expf((x.w - m) * kInvC);
    float lsum = p.x + p.y + p.z + p.w;  // inactive: exp(-huge)=0
    lsum = wave_sum(lsum);
    if (lane == 0) xred[wid] = lsum;
    __syncthreads();
    const float inv = 1.0f / (xred[0] + xred[1] + xred[2] + xred[3]);
    if (act) {
        p.x *= inv; p.y *= inv; p.z *= inv; p.w *= inv;
        A4[t] = p;
    }
}

// ================= Kernel 3: MFMA bmm, NO LDS / NO barriers, q-split partials ==========
// out[b,c,k] = sum_q v[b,c,q]*attn[b,k,q];  GEMM per batch: M=128(c), N=784(k), K=784(q).
// Fragments straight from global (attn/v L2-resident; 32B/lane contiguous per frag row),
// q split 7x128 -> grid 2b*2ct*13kt*7qs = 364 barrier-free blocks.
// Per wave: 16c x 64k tile, 4 ks-steps x {10 dwordx4 loads, cvt to fp16, 4 MFMA}.
// Fragment map (m89-verified): A row=lane&15, k=(lane>>4)*8+j; B col=lane&15, same k;
// D col=lane&15, row=(lane>>4)*4+reg.
constexpr int GN = 64;                    // k cols per block
constexpr int GK = 128;                   // q per slice
constexpr int QSP3 = (kN + GK - 1) / GK;  // 7 (last slice: 16 valid q)
constexpr int NKT3 = (kN + GN - 1) / GN;  // 13

__device__ inline half8v to_h8(const float4 a, const float4 b) {
    half8v h;
    h[0] = (_Float16)a.x; h[1] = (_Float16)a.y; h[2] = (_Float16)a.z; h[3] = (_Float16)a.w;
    h[4] = (_Float16)b.x; h[5] = (_Float16)b.y; h[6] = (_Float16)b.z; h[7] = (_Float16)b.w;
    return h;
}

template <bool ATOMIC>
__global__ __launch_bounds__(256) void bmm_mfma(const float* __restrict__ vg,
                                                const float* __restrict__ attn,
                                                float* __restrict__ P) {
    int bid = blockIdx.x;
    const int qs = bid % QSP3; bid /= QSP3;
    const int kt = bid % NKT3; bid /= NKT3;
    const int ct = bid & 1;    bid >>= 1;
    const int b  = bid;
    const int k0 = kt * GN;
    const int c0 = ct * 64;
    const int q0 = qs * GK;
    const int t  = threadIdx.x;
    const int lane = t & 63;
    const int w = t >> 6;

    const int lrow = lane & 15;           // frag row/col within 16
    const int kgrp = (lane >> 4) * 8;     // q offset of this lane's 8 k-elems

    // Per-lane base pointers (OOB attn rows clamped; junk cols discarded at store).
    const float* vp = vg + (((size_t)b * kC + c0 + 16 * w + lrow) * kN + q0 + kgrp);
    const float* ap[4];
#pragma unroll
    for (int n = 0; n < 4; ++n) {
        const int krow = min(k0 + 16 * n + lrow, kN - 1);
        ap[n] = attn + (((size_t)b * kN + krow) * kN + q0 + kgrp);
    }

    f32x4 acc[4] = {};  // 4 n-frags: wave owns 16 c-rows x 64 k-cols

    if (q0 + GK <= kN) {  // full slice: 4 ks-steps, no predication
#pragma unroll
        for (int ks = 0; ks < GK / 32; ++ks) {
            const int qb = ks * 32;
            const half8v av = to_h8(*reinterpret_cast<const float4*>(vp + qb),
                                    *reinterpret_cast<const float4*>(vp + qb + 4));
#pragma unroll
            for (int n = 0; n < 4; ++n) {
                const half8v bv = to_h8(*reinterpret_cast<const float4*>(ap[n] + qb),
                                        *reinterpret_cast<const float4*>(ap[n] + qb + 4));
                acc[n] = __builtin_amdgcn_mfma_f32_16x16x32_f16(av, bv, acc[n], 0, 0, 0);
            }
        }
    } else {  // tail slice (qs==6): only ks=0 has data; predicate lanes past kN
        const float4 z = make_float4(0.f, 0.f, 0.f, 0.f);
        const bool ok = (q0 + kgrp) < kN;  // spans of 8 never straddle kN (784%16==0)
        const half8v av = to_h8(ok ? *reinterpret_cast<const float4*>(vp) : z,
                                ok ? *reinterpret_cast<const float4*>(vp + 4) : z);
#pragma unroll
        for (int n = 0; n < 4; ++n) {
            const half8v bv = to_h8(ok ? *reinterpret_cast<const float4*>(ap[n]) : z,
                                    ok ? *reinterpret_cast<const float4*>(ap[n] + 4) : z);
            acc[n] = __builtin_amdgcn_mfma_f32_16x16x32_f16(av, bv, acc[n], 0, 0, 0);
        }
    }

    // Epilogue: D col=lane&15, row=(lane>>4)*4+r. Store partial slice (or atomicAdd).
    const int crow = c0 + 16 * w + (lane >> 4) * 4;
    const int kc = k0 + lrow;
#pragma unroll
    for (int n = 0; n < 4; ++n) {
        const int kcol = kc + 16 * n;
        if (kcol < kN) {
            if (ATOMIC) {
#pragma unroll
                for (int r = 0; r < 4; ++r)
                    atomicAdd(&P[((size_t)b * kC + crow + r) * kN + kcol], acc[n][r]);
            } else {
                float* op = P + (((size_t)qs * kB + b) * kC + crow) * kN + kcol;
#pragma unroll
                for (int r = 0; r < 4; ++r) op[(size_t)r * kN] = acc[n][r];
            }
        }
    }
}

// ================= Kernel 4: out = sum_qs partial[qs] =================
// 196 blocks x 256 threads; one float4 per thread; slices L2/L3-resident.
__global__ __launch_bounds__(256) void reduce_kernel(const float* __restrict__ P,
                                                     float* __restrict__ out) {
    const int idx = blockIdx.x * 256 + threadIdx.x;  // < 50176 exactly
    const float4* p = reinterpret_cast<const float4*>(P) + idx;
    float4 s = p[0];
#pragma unroll
    for (int qs = 1; qs < QSP3; ++qs) {
        const float4 v = p[(size_t)qs * (kOutElems / 4)];
        s.x += v.x; s.y += v.y; s.z += v.z; s.w += v.w;
    }
    reinterpret_cast<float4*>(out)[idx] = s;
}

extern "C" void kernel_launch(void* const* d_in, const int* in_sizes, int n_in,
                              void* d_out, int out_size, void* d_ws, size_t ws_size,
                              hipStream_t stream) {
    const float* q = (const float*)d_in[0];
    const float* k = (const float*)d_in[1];
    const float* v = (const float*)d_in[2];

    float* out  = (float*)d_out;               // [B, C, N]
    float* attn = out + kOutElems;             // [B, N, N]
    float* P    = (float*)d_ws;                // [QSP3][B, C, N] partials

    const size_t need = (size_t)QSP3 * kOutElems * sizeof(float);

    if (ws_size >= need) {
        dist_kernel<<<kB * NKTD * NQTD, 256, 0, stream>>>(q, k, attn);
        softmax_kernel<<<kB * kN, 256, 0, stream>>>(attn);
        bmm_mfma<false><<<kB * 2 * NKT3 * QSP3, 256, 0, stream>>>(v, attn, P);
        reduce_kernel<<<(int)(kOutElems / 4 / 256), 256, 0, stream>>>(P, out);
    } else {
        // Fallback without workspace: bmm accumulates into zeroed out via atomics.
        hipMemsetAsync(out, 0, kOutElems * sizeof(float), stream);
        dist_kernel<<<kB * NKTD * NQTD, 256, 0, stream>>>(q, k, attn);
        softmax_kernel<<<kB * kN, 256, 0, stream>>>(attn);
        bmm_mfma<true><<<kB * 2 * NKT3 * QSP3, 256, 0, stream>>>(v, attn, out);
    }
}